// Round 12
// baseline (43.699 us; speedup 1.0000x reference)
//
#include <hip/hip_runtime.h>
#include <math.h>

typedef unsigned long long u64;
typedef unsigned int u32;

#define NB   2
#define L0   4800
#define L1   4800
#define H1C  60
#define W1C  80
#define ROWS 8
#define RPB  (L0 / ROWS)          // 600 row-groups per batch
#define NBLK (NB * RPB)           // 1200 blocks
#define NT   512                  // 8 waves
#define NW   (NT / 64)
#define L14  (L1 / 2)             // 2400 float4 per batch
// partials layout: k in [0,12): {Sm,Sl2,Ssl2,Ss,Sv,Ssq} x {word-mask, byte-mask}

// ---------------------------------------------------------------------------
// Round 12 = r11 with one variable changed: 512-thread blocks under
// __launch_bounds__(512,6) -> 3 blocks/CU x 8 waves = 24 waves/CU capacity
// (r11's (256,4) capped at 16 and averaged ~8). Per-thread main-loop work
// halves; per-block fixed costs unchanged. Direct-L2 pt1 stream (r11 proved
// staging==direct), u64-packed reduce, 8-lane epilogue, separate finalize.
// VGPR cap at 6 waves/SIMD ~ 84 > ~60 needed ((256,6) was spill-free in r10;
// (256,8)'s 64-cap was the spill trigger in r4/r8).
// ---------------------------------------------------------------------------
__global__ __launch_bounds__(NT, 6) void s2ld_main(
    const float* __restrict__ w_pt0,    // [NB][L0][2]
    const float* __restrict__ pt1,      // [NB][L1][2]
    const void*  __restrict__ maskp,    // [NB][L0] word- or byte-bool
    const float* __restrict__ score0,   // [NB][L0]
    const float* __restrict__ score1,   // [NB][L1]
    const float* __restrict__ scale0,   // [NB][2]
    const float* __restrict__ scale1,   // [NB][2]
    float*       __restrict__ partials) // [12][NBLK]
{
    __shared__ u64 redk[ROWS * NW];     // 512 B -- only LDS in the kernel

    const int tid  = threadIdx.x;
    const int blk  = blockIdx.x;
    // parity swizzle: stride-8 XCD round-robin keeps each XCD on one batch's pt1
    const int n    = blk & 1;
    const int rg   = blk >> 1;          // row-group within batch, 0..599
    const int gi0  = n * L0 + rg * ROWS;
    const int lane = tid & 63;
    const int wv   = tid >> 6;

    const float4* p1 = (const float4*)(pt1 + (size_t)n * L1 * 2);
    const float2* p0 = (const float2*)(w_pt0 + (size_t)gi0 * 2);

    // minimize s_j = |q_j|^2 - 2 p.q_j (same order as d2); ax=-2px, ay=-2py.
    float ax[ROWS], ay[ROWS];
    #pragma unroll
    for (int r = 0; r < ROWS; ++r) {
        float2 q = p0[r];
        ax[r] = -2.0f * q.x; ay[r] = -2.0f * q.y;
    }
    float bd[ROWS]; int bj[ROWS];
    #pragma unroll
    for (int r = 0; r < ROWS; ++r) { bd[r] = 3.0e38f; bj[r] = 0; }

    // direct-L2 stream over pt1; j ascends per thread => first-occurrence
    // argmin within a thread; cross-thread ties resolved in the u64 reduce.
    for (int j4 = tid; j4 < L14; j4 += NT) {
        const float4 q = p1[j4];
        const float c0 = fmaf(q.x, q.x, q.y * q.y);
        const float c1 = fmaf(q.z, q.z, q.w * q.w);
        const int j0 = 2 * j4;
        #pragma unroll
        for (int r = 0; r < ROWS; ++r) {
            float s0 = fmaf(ax[r], q.x, fmaf(ay[r], q.y, c0));
            if (s0 < bd[r]) { bd[r] = s0; bj[r] = j0; }
            float s1 = fmaf(ax[r], q.z, fmaf(ay[r], q.w, c1));
            if (s1 < bd[r]) { bd[r] = s1; bj[r] = j0 + 1; }
        }
    }

    // pack (monotone-transformed s, j) into u64: min_u64 == (min s, then min j)
    #pragma unroll
    for (int r = 0; r < ROWS; ++r) {
        u32 b = __float_as_uint(bd[r]);
        u32 t = b ^ ((u32)((int)b >> 31) | 0x80000000u);   // IEEE->monotone u32
        u64 key = ((u64)t << 32) | (u32)bj[r];
        #pragma unroll
        for (int off = 32; off; off >>= 1) {
            u64 ok = __shfl_xor(key, off);
            if (ok < key) key = ok;
        }
        if (lane == 0) redk[r * NW + wv] = key;
    }
    __syncthreads();                    // the kernel's only barrier

    // parallel epilogue: lane r (< 8, wave 0) handles row r
    if (tid < ROWS) {
        const int r = tid;
        u64 key = redk[r * NW + 0];
        #pragma unroll
        for (int w = 1; w < NW; ++w) {
            u64 ok = redk[r * NW + w];
            if (ok < key) key = ok;
        }
        const int jj = (int)(u32)key;
        const int gi = gi0 + r;
        const float2 q0 = ((const float2*)w_pt0)[gi];
        const float2 q1 = ((const float2*)(pt1 + (size_t)n * L1 * 2))[jj];
        const float dx = q0.x - q1.x, dy = q0.y - q1.y;
        const float l2 = sqrtf(dx * dx + dy * dy);         // exact d2

        const float thr = 8.0f * scale0[n * 2 + 0];
        const float sxd = ((float)W1C * scale1[n * 2 + 0] * 8.0f - 1.0f) * 0.5f;
        const float syd = ((float)H1C * scale1[n * 2 + 1] * 8.0f - 1.0f) * 0.5f;
        const float* im = score1 + (size_t)n * L1;

        // both mask interpretations (int32 and float32 agree on word != 0)
        const float mw = (((const u32*)maskp)[gi] != 0u) ? 1.0f : 0.0f;
        const float mb = (((const unsigned char*)maskp)[gi] != 0) ? 1.0f : 0.0f;
        const float inthr = (l2 <= thr) ? 1.0f : 0.0f;

        const float s0v  = score0[gi];
        const float ssum = im[jj] + s0v;

        // bilinear grid-sample of score1 as 60x80 image, zeros outside
        const float gx = (q0.x / sxd) * 0.5f * (float)(W1C - 1);
        const float gy = (q0.y / syd) * 0.5f * (float)(H1C - 1);
        const float x0 = floorf(gx), y0 = floorf(gy);
        const float x1 = x0 + 1.0f,  y1 = y0 + 1.0f;
        const float wx1 = gx - x0, wx0 = 1.0f - wx1;
        const float wy1 = gy - y0, wy0 = 1.0f - wy1;

        auto corner = [&](float xf, float yf) -> float {
            bool inb = (xf >= 0.0f) && (xf <= (float)(W1C - 1)) &&
                       (yf >= 0.0f) && (yf <= (float)(H1C - 1));
            int xc = (int)fminf(fmaxf(xf, 0.0f), (float)(W1C - 1));
            int yc = (int)fminf(fmaxf(yf, 0.0f), (float)(H1C - 1));
            float v = im[yc * W1C + xc];
            return inb ? v : 0.0f;
        };
        const float res = corner(x0, y0) * wx0 * wy0
                        + corner(x1, y0) * wx1 * wy0
                        + corner(x0, y1) * wx0 * wy1
                        + corner(x1, y1) * wx1 * wy1;
        const float dsc = res - s0v;
        const float dsq = dsc * dsc;

        const float dvw = inthr * mw, dvb = inthr * mb;
        float v0  = dvw,        v1 = l2 * dvw,  v2  = ssum * l2 * dvw;
        float v3  = ssum * dvw, v4 = mw,        v5  = dsq * mw;
        float v6  = dvb,        v7 = l2 * dvb,  v8  = ssum * l2 * dvb;
        float v9  = ssum * dvb, v10 = mb,       v11 = dsq * mb;
#define RED8(V) { V += __shfl_xor(V, 4); V += __shfl_xor(V, 2); V += __shfl_xor(V, 1); }
        RED8(v0) RED8(v1) RED8(v2) RED8(v3) RED8(v4)  RED8(v5)
        RED8(v6) RED8(v7) RED8(v8) RED8(v9) RED8(v10) RED8(v11)
#undef RED8
        if (tid == 0) {
            partials[ 0 * NBLK + blk] = v0;  partials[ 1 * NBLK + blk] = v1;
            partials[ 2 * NBLK + blk] = v2;  partials[ 3 * NBLK + blk] = v3;
            partials[ 4 * NBLK + blk] = v4;  partials[ 5 * NBLK + blk] = v5;
            partials[ 6 * NBLK + blk] = v6;  partials[ 7 * NBLK + blk] = v7;
            partials[ 8 * NBLK + blk] = v8;  partials[ 9 * NBLK + blk] = v9;
            partials[10 * NBLK + blk] = v10; partials[11 * NBLK + blk] = v11;
        }
    }
}

// ---------------------------------------------------------------------------
// Finalize: one block. Detects mask format, reduces 12 partial arrays, emits.
// ---------------------------------------------------------------------------
__global__ __launch_bounds__(256) void s2ld_finalize(
    const float* __restrict__ partials,
    const void*  __restrict__ maskp,
    float*       __restrict__ out)
{
    __shared__ float fin[12 * 4];
    __shared__ u32   sbad;

    const int tid  = threadIdx.x;
    const int lane = tid & 63;
    const int wv   = tid >> 6;

    if (tid == 0) sbad = 0u;
    __syncthreads();
    {
        // mask format detection (first 2400 words in-bounds for all layouts)
        u32 bad = 0u;
        const u32* mwp = (const u32*)maskp;
        for (int i = tid; i < 2400; i += 256) {
            u32 w = mwp[i];
            if (w != 0u && w != 1u && w != 0x3f800000u) bad = 1u;
        }
        atomicOr(&sbad, bad);
    }

    for (int k = 0; k < 12; ++k) {
        float s = 0.0f;
        for (int rbl = tid; rbl < NBLK; rbl += 256) s += partials[k * NBLK + rbl];
        #pragma unroll
        for (int off = 32; off; off >>= 1) s += __shfl_xor(s, off);
        if (lane == 0) fin[k * 4 + wv] = s;
    }
    __syncthreads();

    if (tid == 0) {
        const int o = (sbad == 0u) ? 0 : 6;   // word-format vs byte-format
        float S[6];
        #pragma unroll
        for (int k = 0; k < 6; ++k) {
            float s = 0.0f;
            #pragma unroll
            for (int w = 0; w < 4; ++w) s += fin[(o + k) * 4 + w];
            S[k] = s;
        }
        const float den = fmaxf(S[0], 1.0f);
        const float lm  = S[1] / den;
        out[0] = lm;                              // loc_loss_mean
        out[1] = (S[2] - lm * S[3]) / den;        // rep_loss_mean
        out[2] = 2.0f * S[5] / fmaxf(S[4], 1.0f); // score_loss
    }
}

extern "C" void kernel_launch(void* const* d_in, const int* in_sizes, int n_in,
                              void* d_out, int out_size, void* d_ws, size_t ws_size,
                              hipStream_t stream) {
    const float* w_pt0  = (const float*)d_in[0];
    const float* pt1    = (const float*)d_in[1];
    const void*  maskp  =               d_in[2];
    const float* score0 = (const float*)d_in[3];
    const float* score1 = (const float*)d_in[4];
    // d_in[5] = image1 (zeros) -- unused
    const float* scale0 = (const float*)d_in[6];
    const float* scale1 = (const float*)d_in[7];

    float* partials = (float*)d_ws;   // 12 * 1200 * 4 B, fully rewritten

    s2ld_main<<<NBLK, NT, 0, stream>>>(w_pt0, pt1, maskp, score0, score1,
                                       scale0, scale1, partials);
    s2ld_finalize<<<1, 256, 0, stream>>>(partials, maskp, (float*)d_out);
}

// Round 13
// 39.386 us; speedup vs baseline: 1.1095x; 1.1095x over previous
//
#include <hip/hip_runtime.h>
#include <math.h>

typedef unsigned long long u64;
typedef unsigned int u32;

#define NB   2
#define L0   4800
#define L1   4800
#define H1C  60
#define W1C  80
#define ROWS 8
#define RPB  (L0 / ROWS)          // 600 row-groups per batch
#define NBLK (NB * RPB)           // 1200 blocks
#define NT   256                  // 4 waves (r11 geometry -- best measured)
#define NW   (NT / 64)
#define L14  (L1 / 2)             // 2400 float4 per batch = 9*256 + 96
// partials layout: k in [0,12): {Sm,Sl2,Ssl2,Ss,Sv,Ssq} x {word-mask, byte-mask}

// ---------------------------------------------------------------------------
// Round 13 = r11 with ONE change: the 9.4-iteration runtime streaming loop is
// replaced by a fully-unrolled load phase -- 9 uniform + 1 masked float4 load
// into NAMED registers (all 10 addresses independent, hoisted above compute)
// -- then a pure-VALU compute phase. One vmcnt drain per wave instead of ~9
// serialized L2-latency stalls. ~100 VGPR < 128 cap of (256,4), which is the
// only bound proven spill-free (r1/r6/r7; bare/(256,8) spill -> WRITE 487KB).
// ---------------------------------------------------------------------------
__global__ __launch_bounds__(NT, 4) void s2ld_main(
    const float* __restrict__ w_pt0,    // [NB][L0][2]
    const float* __restrict__ pt1,      // [NB][L1][2]
    const void*  __restrict__ maskp,    // [NB][L0] word- or byte-bool
    const float* __restrict__ score0,   // [NB][L0]
    const float* __restrict__ score1,   // [NB][L1]
    const float* __restrict__ scale0,   // [NB][2]
    const float* __restrict__ scale1,   // [NB][2]
    float*       __restrict__ partials) // [12][NBLK]
{
    __shared__ u64 redk[ROWS * NW];     // 256 B -- only LDS in the kernel

    const int tid  = threadIdx.x;
    const int blk  = blockIdx.x;
    // parity swizzle: stride-8 XCD round-robin keeps each XCD on one batch's pt1
    const int n    = blk & 1;
    const int rg   = blk >> 1;          // row-group within batch, 0..599
    const int gi0  = n * L0 + rg * ROWS;
    const int lane = tid & 63;
    const int wv   = tid >> 6;

    const float4* p1 = (const float4*)(pt1 + (size_t)n * L1 * 2);
    const float2* p0 = (const float2*)(w_pt0 + (size_t)gi0 * 2);

    // ---- LOAD PHASE: all 10 independent loads issued back-to-back ----------
    const float4 q0 = p1[tid];
    const float4 q1 = p1[tid +  256];
    const float4 q2 = p1[tid +  512];
    const float4 q3 = p1[tid +  768];
    const float4 q4 = p1[tid + 1024];
    const float4 q5 = p1[tid + 1280];
    const float4 q6 = p1[tid + 1536];
    const float4 q7 = p1[tid + 1792];
    const float4 q8 = p1[tid + 2048];
    float4 q9 = make_float4(0.f, 0.f, 0.f, 0.f);
    const bool tail = (tid < L14 - 9 * 256);        // 96 threads
    if (tail) q9 = p1[tid + 2304];

    // minimize s_j = |q_j|^2 - 2 p.q_j (same order as d2); ax=-2px, ay=-2py.
    float ax[ROWS], ay[ROWS];
    #pragma unroll
    for (int r = 0; r < ROWS; ++r) {
        float2 q = p0[r];
        ax[r] = -2.0f * q.x; ay[r] = -2.0f * q.y;
    }
    float bd[ROWS]; int bj[ROWS];
    #pragma unroll
    for (int r = 0; r < ROWS; ++r) { bd[r] = 3.0e38f; bj[r] = 0; }

    // ---- COMPUTE PHASE: pure VALU; j ascends per thread => first-occurrence
    // argmin within a thread; cross-thread ties resolved in the u64 reduce.
#define COMP(Q, STEP) {                                               \
        const float c0 = fmaf(Q.x, Q.x, Q.y * Q.y);                   \
        const float c1 = fmaf(Q.z, Q.z, Q.w * Q.w);                   \
        const int j0 = 2 * (tid + (STEP) * 256);                      \
        _Pragma("unroll")                                             \
        for (int r = 0; r < ROWS; ++r) {                              \
            float s0 = fmaf(ax[r], Q.x, fmaf(ay[r], Q.y, c0));        \
            if (s0 < bd[r]) { bd[r] = s0; bj[r] = j0; }               \
            float s1 = fmaf(ax[r], Q.z, fmaf(ay[r], Q.w, c1));        \
            if (s1 < bd[r]) { bd[r] = s1; bj[r] = j0 + 1; }           \
        } }

    COMP(q0, 0) COMP(q1, 1) COMP(q2, 2) COMP(q3, 3) COMP(q4, 4)
    COMP(q5, 5) COMP(q6, 6) COMP(q7, 7) COMP(q8, 8)
    if (tail) COMP(q9, 9)
#undef COMP

    // pack (monotone-transformed s, j) into u64: min_u64 == (min s, then min j)
    #pragma unroll
    for (int r = 0; r < ROWS; ++r) {
        u32 b = __float_as_uint(bd[r]);
        u32 t = b ^ ((u32)((int)b >> 31) | 0x80000000u);   // IEEE->monotone u32
        u64 key = ((u64)t << 32) | (u32)bj[r];
        #pragma unroll
        for (int off = 32; off; off >>= 1) {
            u64 ok = __shfl_xor(key, off);
            if (ok < key) key = ok;
        }
        if (lane == 0) redk[r * NW + wv] = key;
    }
    __syncthreads();                    // the kernel's only barrier

    // parallel epilogue: lane r (< 8, wave 0) handles row r
    if (tid < ROWS) {
        const int r = tid;
        u64 key = redk[r * NW + 0];
        #pragma unroll
        for (int w = 1; w < NW; ++w) {
            u64 ok = redk[r * NW + w];
            if (ok < key) key = ok;
        }
        const int jj = (int)(u32)key;
        const int gi = gi0 + r;
        const float2 qp = ((const float2*)w_pt0)[gi];
        const float2 qn = ((const float2*)(pt1 + (size_t)n * L1 * 2))[jj];
        const float dx = qp.x - qn.x, dy = qp.y - qn.y;
        const float l2 = sqrtf(dx * dx + dy * dy);         // exact d2

        const float thr = 8.0f * scale0[n * 2 + 0];
        const float sxd = ((float)W1C * scale1[n * 2 + 0] * 8.0f - 1.0f) * 0.5f;
        const float syd = ((float)H1C * scale1[n * 2 + 1] * 8.0f - 1.0f) * 0.5f;
        const float* im = score1 + (size_t)n * L1;

        // both mask interpretations (int32 and float32 agree on word != 0)
        const float mw = (((const u32*)maskp)[gi] != 0u) ? 1.0f : 0.0f;
        const float mb = (((const unsigned char*)maskp)[gi] != 0) ? 1.0f : 0.0f;
        const float inthr = (l2 <= thr) ? 1.0f : 0.0f;

        const float s0v  = score0[gi];
        const float ssum = im[jj] + s0v;

        // bilinear grid-sample of score1 as 60x80 image, zeros outside
        const float gx = (qp.x / sxd) * 0.5f * (float)(W1C - 1);
        const float gy = (qp.y / syd) * 0.5f * (float)(H1C - 1);
        const float x0 = floorf(gx), y0 = floorf(gy);
        const float x1 = x0 + 1.0f,  y1 = y0 + 1.0f;
        const float wx1 = gx - x0, wx0 = 1.0f - wx1;
        const float wy1 = gy - y0, wy0 = 1.0f - wy1;

        auto corner = [&](float xf, float yf) -> float {
            bool inb = (xf >= 0.0f) && (xf <= (float)(W1C - 1)) &&
                       (yf >= 0.0f) && (yf <= (float)(H1C - 1));
            int xc = (int)fminf(fmaxf(xf, 0.0f), (float)(W1C - 1));
            int yc = (int)fminf(fmaxf(yf, 0.0f), (float)(H1C - 1));
            float v = im[yc * W1C + xc];
            return inb ? v : 0.0f;
        };
        const float res = corner(x0, y0) * wx0 * wy0
                        + corner(x1, y0) * wx1 * wy0
                        + corner(x0, y1) * wx0 * wy1
                        + corner(x1, y1) * wx1 * wy1;
        const float dsc = res - s0v;
        const float dsq = dsc * dsc;

        const float dvw = inthr * mw, dvb = inthr * mb;
        float v0  = dvw,        v1 = l2 * dvw,  v2  = ssum * l2 * dvw;
        float v3  = ssum * dvw, v4 = mw,        v5  = dsq * mw;
        float v6  = dvb,        v7 = l2 * dvb,  v8  = ssum * l2 * dvb;
        float v9  = ssum * dvb, v10 = mb,       v11 = dsq * mb;
#define RED8(V) { V += __shfl_xor(V, 4); V += __shfl_xor(V, 2); V += __shfl_xor(V, 1); }
        RED8(v0) RED8(v1) RED8(v2) RED8(v3) RED8(v4)  RED8(v5)
        RED8(v6) RED8(v7) RED8(v8) RED8(v9) RED8(v10) RED8(v11)
#undef RED8
        if (tid == 0) {
            partials[ 0 * NBLK + blk] = v0;  partials[ 1 * NBLK + blk] = v1;
            partials[ 2 * NBLK + blk] = v2;  partials[ 3 * NBLK + blk] = v3;
            partials[ 4 * NBLK + blk] = v4;  partials[ 5 * NBLK + blk] = v5;
            partials[ 6 * NBLK + blk] = v6;  partials[ 7 * NBLK + blk] = v7;
            partials[ 8 * NBLK + blk] = v8;  partials[ 9 * NBLK + blk] = v9;
            partials[10 * NBLK + blk] = v10; partials[11 * NBLK + blk] = v11;
        }
    }
}

// ---------------------------------------------------------------------------
// Finalize: one block. Detects mask format, reduces 12 partial arrays, emits.
// ---------------------------------------------------------------------------
__global__ __launch_bounds__(NT) void s2ld_finalize(
    const float* __restrict__ partials,
    const void*  __restrict__ maskp,
    float*       __restrict__ out)
{
    __shared__ float fin[12 * NW];
    __shared__ u32   sbad;

    const int tid  = threadIdx.x;
    const int lane = tid & 63;
    const int wv   = tid >> 6;

    if (tid == 0) sbad = 0u;
    __syncthreads();
    {
        // mask format detection (first 2400 words in-bounds for all layouts)
        u32 bad = 0u;
        const u32* mwp = (const u32*)maskp;
        for (int i = tid; i < 2400; i += NT) {
            u32 w = mwp[i];
            if (w != 0u && w != 1u && w != 0x3f800000u) bad = 1u;
        }
        atomicOr(&sbad, bad);
    }

    for (int k = 0; k < 12; ++k) {
        float s = 0.0f;
        for (int rbl = tid; rbl < NBLK; rbl += NT) s += partials[k * NBLK + rbl];
        #pragma unroll
        for (int off = 32; off; off >>= 1) s += __shfl_xor(s, off);
        if (lane == 0) fin[k * NW + wv] = s;
    }
    __syncthreads();

    if (tid == 0) {
        const int o = (sbad == 0u) ? 0 : 6;   // word-format vs byte-format
        float S[6];
        #pragma unroll
        for (int k = 0; k < 6; ++k) {
            float s = 0.0f;
            #pragma unroll
            for (int w = 0; w < NW; ++w) s += fin[(o + k) * NW + w];
            S[k] = s;
        }
        const float den = fmaxf(S[0], 1.0f);
        const float lm  = S[1] / den;
        out[0] = lm;                              // loc_loss_mean
        out[1] = (S[2] - lm * S[3]) / den;        // rep_loss_mean
        out[2] = 2.0f * S[5] / fmaxf(S[4], 1.0f); // score_loss
    }
}

extern "C" void kernel_launch(void* const* d_in, const int* in_sizes, int n_in,
                              void* d_out, int out_size, void* d_ws, size_t ws_size,
                              hipStream_t stream) {
    const float* w_pt0  = (const float*)d_in[0];
    const float* pt1    = (const float*)d_in[1];
    const void*  maskp  =               d_in[2];
    const float* score0 = (const float*)d_in[3];
    const float* score1 = (const float*)d_in[4];
    // d_in[5] = image1 (zeros) -- unused
    const float* scale0 = (const float*)d_in[6];
    const float* scale1 = (const float*)d_in[7];

    float* partials = (float*)d_ws;   // 12 * 1200 * 4 B, fully rewritten

    s2ld_main<<<NBLK, NT, 0, stream>>>(w_pt0, pt1, maskp, score0, score1,
                                       scale0, scale1, partials);
    s2ld_finalize<<<1, NT, 0, stream>>>(partials, maskp, (float*)d_out);
}

// Round 14
// 36.767 us; speedup vs baseline: 1.1885x; 1.0712x over previous
//
#include <hip/hip_runtime.h>
#include <math.h>

typedef unsigned long long u64;
typedef unsigned int u32;

#define NB   2
#define L0   4800
#define L1   4800
#define H1C  60
#define W1C  80
#define ROWS 16
#define RPB  (L0 / ROWS)          // 300 row-groups per batch
#define NBLK (NB * RPB)           // 600 blocks
#define NT   256                  // 4 waves (champion geometry)
#define NW   (NT / 64)
#define L14  (L1 / 2)             // 2400 float4 per batch
// partials layout: k in [0,12): {Sm,Sl2,Ssl2,Ss,Sv,Ssq} x {word-mask, byte-mask}

// ---------------------------------------------------------------------------
// Round 14 -- clean test of the per-block fixed-cost model. Single-variable
// delta off the r13 champion: NBLK 1200->600, ROWS 8->16 (each pt1 float4
// serves 16 rows; total load traffic halves; per-block fixed costs paid half
// as often). All prior fat-block tests (r6/r7) were confounded by full-tile
// LDS (-6us when removed, r9->r10) and the fused atomic tail (-3us, r8->r9);
// this one has neither: direct-L2 stream, 256B LDS, split finalize.
// (256,4): 128-VGPR cap, the only bound proven spill-free. Arrays with
// constant-bound unrolled loops stay in registers (r1/r5 evidence).
// ---------------------------------------------------------------------------
__global__ __launch_bounds__(NT, 4) void s2ld_main(
    const float* __restrict__ w_pt0,    // [NB][L0][2]
    const float* __restrict__ pt1,      // [NB][L1][2]
    const void*  __restrict__ maskp,    // [NB][L0] word- or byte-bool
    const float* __restrict__ score0,   // [NB][L0]
    const float* __restrict__ score1,   // [NB][L1]
    const float* __restrict__ scale0,   // [NB][2]
    const float* __restrict__ scale1,   // [NB][2]
    float*       __restrict__ partials) // [12][NBLK]
{
    __shared__ u64 redk[ROWS * NW];     // 512 B -- only LDS in the kernel

    const int tid  = threadIdx.x;
    const int blk  = blockIdx.x;
    // parity swizzle: stride-8 XCD round-robin keeps each XCD on one batch's pt1
    const int n    = blk & 1;
    const int rg   = blk >> 1;          // row-group within batch, 0..299
    const int gi0  = n * L0 + rg * ROWS;
    const int lane = tid & 63;
    const int wv   = tid >> 6;

    const float4* p1 = (const float4*)(pt1 + (size_t)n * L1 * 2);
    const float4* p0 = (const float4*)(w_pt0 + (size_t)gi0 * 2);  // 8 float4

    // minimize s_j = |q_j|^2 - 2 p.q_j (same order as d2); ax=-2px, ay=-2py.
    float ax[ROWS], ay[ROWS];
    #pragma unroll
    for (int h = 0; h < ROWS / 2; ++h) {
        float4 f = p0[h];
        ax[2*h]   = -2.0f * f.x; ay[2*h]   = -2.0f * f.y;
        ax[2*h+1] = -2.0f * f.z; ay[2*h+1] = -2.0f * f.w;
    }
    float bd[ROWS]; int bj[ROWS];
    #pragma unroll
    for (int r = 0; r < ROWS; ++r) { bd[r] = 3.0e38f; bj[r] = 0; }

    // direct-L2 stream over pt1; each float4 serves all 16 rows. j ascends
    // per thread => first-occurrence argmin within a thread; cross-thread
    // ties resolved in the u64 reduce.
    for (int j4 = tid; j4 < L14; j4 += NT) {
        const float4 q = p1[j4];
        const float c0 = fmaf(q.x, q.x, q.y * q.y);
        const float c1 = fmaf(q.z, q.z, q.w * q.w);
        const int j0 = 2 * j4;
        #pragma unroll
        for (int r = 0; r < ROWS; ++r) {
            float s0 = fmaf(ax[r], q.x, fmaf(ay[r], q.y, c0));
            if (s0 < bd[r]) { bd[r] = s0; bj[r] = j0; }
            float s1 = fmaf(ax[r], q.z, fmaf(ay[r], q.w, c1));
            if (s1 < bd[r]) { bd[r] = s1; bj[r] = j0 + 1; }
        }
    }

    // pack (monotone-transformed s, j) into u64: min_u64 == (min s, then min j)
    #pragma unroll
    for (int r = 0; r < ROWS; ++r) {
        u32 b = __float_as_uint(bd[r]);
        u32 t = b ^ ((u32)((int)b >> 31) | 0x80000000u);   // IEEE->monotone u32
        u64 key = ((u64)t << 32) | (u32)bj[r];
        #pragma unroll
        for (int off = 32; off; off >>= 1) {
            u64 ok = __shfl_xor(key, off);
            if (ok < key) key = ok;
        }
        if (lane == 0) redk[r * NW + wv] = key;
    }
    __syncthreads();                    // the kernel's only barrier

    // parallel epilogue: lane r (< 16, all wave 0) handles row r
    if (tid < ROWS) {
        const int r = tid;
        u64 key = redk[r * NW + 0];
        #pragma unroll
        for (int w = 1; w < NW; ++w) {
            u64 ok = redk[r * NW + w];
            if (ok < key) key = ok;
        }
        const int jj = (int)(u32)key;
        const int gi = gi0 + r;
        const float2 qp = ((const float2*)w_pt0)[gi];
        const float2 qn = ((const float2*)(pt1 + (size_t)n * L1 * 2))[jj];
        const float dx = qp.x - qn.x, dy = qp.y - qn.y;
        const float l2 = sqrtf(dx * dx + dy * dy);         // exact d2

        const float thr = 8.0f * scale0[n * 2 + 0];
        const float sxd = ((float)W1C * scale1[n * 2 + 0] * 8.0f - 1.0f) * 0.5f;
        const float syd = ((float)H1C * scale1[n * 2 + 1] * 8.0f - 1.0f) * 0.5f;
        const float* im = score1 + (size_t)n * L1;

        // both mask interpretations (int32 and float32 agree on word != 0)
        const float mw = (((const u32*)maskp)[gi] != 0u) ? 1.0f : 0.0f;
        const float mb = (((const unsigned char*)maskp)[gi] != 0) ? 1.0f : 0.0f;
        const float inthr = (l2 <= thr) ? 1.0f : 0.0f;

        const float s0v  = score0[gi];
        const float ssum = im[jj] + s0v;

        // bilinear grid-sample of score1 as 60x80 image, zeros outside
        const float gx = (qp.x / sxd) * 0.5f * (float)(W1C - 1);
        const float gy = (qp.y / syd) * 0.5f * (float)(H1C - 1);
        const float x0 = floorf(gx), y0 = floorf(gy);
        const float x1 = x0 + 1.0f,  y1 = y0 + 1.0f;
        const float wx1 = gx - x0, wx0 = 1.0f - wx1;
        const float wy1 = gy - y0, wy0 = 1.0f - wy1;

        auto corner = [&](float xf, float yf) -> float {
            bool inb = (xf >= 0.0f) && (xf <= (float)(W1C - 1)) &&
                       (yf >= 0.0f) && (yf <= (float)(H1C - 1));
            int xc = (int)fminf(fmaxf(xf, 0.0f), (float)(W1C - 1));
            int yc = (int)fminf(fmaxf(yf, 0.0f), (float)(H1C - 1));
            float v = im[yc * W1C + xc];
            return inb ? v : 0.0f;
        };
        const float res = corner(x0, y0) * wx0 * wy0
                        + corner(x1, y0) * wx1 * wy0
                        + corner(x0, y1) * wx0 * wy1
                        + corner(x1, y1) * wx1 * wy1;
        const float dsc = res - s0v;
        const float dsq = dsc * dsc;

        const float dvw = inthr * mw, dvb = inthr * mb;
        float v0  = dvw,        v1 = l2 * dvw,  v2  = ssum * l2 * dvw;
        float v3  = ssum * dvw, v4 = mw,        v5  = dsq * mw;
        float v6  = dvb,        v7 = l2 * dvb,  v8  = ssum * l2 * dvb;
        float v9  = ssum * dvb, v10 = mb,       v11 = dsq * mb;
#define RED16(V) { V += __shfl_xor(V, 8); V += __shfl_xor(V, 4); \
                   V += __shfl_xor(V, 2); V += __shfl_xor(V, 1); }
        RED16(v0) RED16(v1) RED16(v2) RED16(v3) RED16(v4)  RED16(v5)
        RED16(v6) RED16(v7) RED16(v8) RED16(v9) RED16(v10) RED16(v11)
#undef RED16
        if (tid == 0) {
            partials[ 0 * NBLK + blk] = v0;  partials[ 1 * NBLK + blk] = v1;
            partials[ 2 * NBLK + blk] = v2;  partials[ 3 * NBLK + blk] = v3;
            partials[ 4 * NBLK + blk] = v4;  partials[ 5 * NBLK + blk] = v5;
            partials[ 6 * NBLK + blk] = v6;  partials[ 7 * NBLK + blk] = v7;
            partials[ 8 * NBLK + blk] = v8;  partials[ 9 * NBLK + blk] = v9;
            partials[10 * NBLK + blk] = v10; partials[11 * NBLK + blk] = v11;
        }
    }
}

// ---------------------------------------------------------------------------
// Finalize: one block. Detects mask format, reduces 12 partial arrays, emits.
// ---------------------------------------------------------------------------
__global__ __launch_bounds__(NT) void s2ld_finalize(
    const float* __restrict__ partials,
    const void*  __restrict__ maskp,
    float*       __restrict__ out)
{
    __shared__ float fin[12 * NW];
    __shared__ u32   sbad;

    const int tid  = threadIdx.x;
    const int lane = tid & 63;
    const int wv   = tid >> 6;

    if (tid == 0) sbad = 0u;
    __syncthreads();
    {
        // mask format detection (first 2400 words in-bounds for all layouts)
        u32 bad = 0u;
        const u32* mwp = (const u32*)maskp;
        for (int i = tid; i < 2400; i += NT) {
            u32 w = mwp[i];
            if (w != 0u && w != 1u && w != 0x3f800000u) bad = 1u;
        }
        atomicOr(&sbad, bad);
    }

    for (int k = 0; k < 12; ++k) {
        float s = 0.0f;
        for (int rbl = tid; rbl < NBLK; rbl += NT) s += partials[k * NBLK + rbl];
        #pragma unroll
        for (int off = 32; off; off >>= 1) s += __shfl_xor(s, off);
        if (lane == 0) fin[k * NW + wv] = s;
    }
    __syncthreads();

    if (tid == 0) {
        const int o = (sbad == 0u) ? 0 : 6;   // word-format vs byte-format
        float S[6];
        #pragma unroll
        for (int k = 0; k < 6; ++k) {
            float s = 0.0f;
            #pragma unroll
            for (int w = 0; w < NW; ++w) s += fin[(o + k) * NW + w];
            S[k] = s;
        }
        const float den = fmaxf(S[0], 1.0f);
        const float lm  = S[1] / den;
        out[0] = lm;                              // loc_loss_mean
        out[1] = (S[2] - lm * S[3]) / den;        // rep_loss_mean
        out[2] = 2.0f * S[5] / fmaxf(S[4], 1.0f); // score_loss
    }
}

extern "C" void kernel_launch(void* const* d_in, const int* in_sizes, int n_in,
                              void* d_out, int out_size, void* d_ws, size_t ws_size,
                              hipStream_t stream) {
    const float* w_pt0  = (const float*)d_in[0];
    const float* pt1    = (const float*)d_in[1];
    const void*  maskp  =               d_in[2];
    const float* score0 = (const float*)d_in[3];
    const float* score1 = (const float*)d_in[4];
    // d_in[5] = image1 (zeros) -- unused
    const float* scale0 = (const float*)d_in[6];
    const float* scale1 = (const float*)d_in[7];

    float* partials = (float*)d_ws;   // 12 * 600 * 4 B, fully rewritten

    s2ld_main<<<NBLK, NT, 0, stream>>>(w_pt0, pt1, maskp, score0, score1,
                                       scale0, scale1, partials);
    s2ld_finalize<<<1, NT, 0, stream>>>(partials, maskp, (float*)d_out);
}

// Round 15
// 35.447 us; speedup vs baseline: 1.2328x; 1.0372x over previous
//
#include <hip/hip_runtime.h>
#include <math.h>

typedef unsigned long long u64;
typedef unsigned int u32;

#define NB   2
#define L0   4800
#define L1   4800
#define H1C  60
#define W1C  80
#define ROWS 24
#define RPB  (L0 / ROWS)          // 200 row-groups per batch
#define NBLK (NB * RPB)           // 400 blocks
#define NT   256                  // 4 waves (champion geometry)
#define NW   (NT / 64)
#define L14  (L1 / 2)             // 2400 float4 per batch
// partials layout: k in [0,12): {Sm,Sl2,Ssl2,Ss,Sv,Ssq} x {word-mask, byte-mask}

// ---------------------------------------------------------------------------
// Round 15 -- continue the only confirmed trend (fewer, fatter blocks):
// ROWS 16->24, NBLK 600->400. Each pt1 float4 now serves 24 rows (load
// traffic -33%), per-block fixed cost paid 400x. State ~120 VGPR, so
// __launch_bounds__(256,3) (cap ~168) instead of (256,4)'s marginal 128.
// Grid fills only ~1.6 waves/SIMD regardless, so the lower bound is free.
// Everything else identical to the r13/r14 champion: direct-L2 stream,
// u64-packed reduce, split finalize, parity XCD swizzle.
// ---------------------------------------------------------------------------
__global__ __launch_bounds__(NT, 3) void s2ld_main(
    const float* __restrict__ w_pt0,    // [NB][L0][2]
    const float* __restrict__ pt1,      // [NB][L1][2]
    const void*  __restrict__ maskp,    // [NB][L0] word- or byte-bool
    const float* __restrict__ score0,   // [NB][L0]
    const float* __restrict__ score1,   // [NB][L1]
    const float* __restrict__ scale0,   // [NB][2]
    const float* __restrict__ scale1,   // [NB][2]
    float*       __restrict__ partials) // [12][NBLK]
{
    __shared__ u64 redk[ROWS * NW];     // 768 B -- only LDS in the kernel

    const int tid  = threadIdx.x;
    const int blk  = blockIdx.x;
    // parity swizzle: stride-8 XCD round-robin keeps each XCD on one batch's pt1
    const int n    = blk & 1;
    const int rg   = blk >> 1;          // row-group within batch, 0..199
    const int gi0  = n * L0 + rg * ROWS;
    const int lane = tid & 63;
    const int wv   = tid >> 6;

    const float4* p1 = (const float4*)(pt1 + (size_t)n * L1 * 2);
    const float4* p0 = (const float4*)(w_pt0 + (size_t)gi0 * 2);  // 12 float4

    // minimize s_j = |q_j|^2 - 2 p.q_j (same order as d2); ax=-2px, ay=-2py.
    float ax[ROWS], ay[ROWS];
    #pragma unroll
    for (int h = 0; h < ROWS / 2; ++h) {
        float4 f = p0[h];
        ax[2*h]   = -2.0f * f.x; ay[2*h]   = -2.0f * f.y;
        ax[2*h+1] = -2.0f * f.z; ay[2*h+1] = -2.0f * f.w;
    }
    float bd[ROWS]; int bj[ROWS];
    #pragma unroll
    for (int r = 0; r < ROWS; ++r) { bd[r] = 3.0e38f; bj[r] = 0; }

    // direct-L2 stream over pt1; each float4 serves all 24 rows. j ascends
    // per thread => first-occurrence argmin within a thread; cross-thread
    // ties resolved in the u64 reduce.
    for (int j4 = tid; j4 < L14; j4 += NT) {
        const float4 q = p1[j4];
        const float c0 = fmaf(q.x, q.x, q.y * q.y);
        const float c1 = fmaf(q.z, q.z, q.w * q.w);
        const int j0 = 2 * j4;
        #pragma unroll
        for (int r = 0; r < ROWS; ++r) {
            float s0 = fmaf(ax[r], q.x, fmaf(ay[r], q.y, c0));
            if (s0 < bd[r]) { bd[r] = s0; bj[r] = j0; }
            float s1 = fmaf(ax[r], q.z, fmaf(ay[r], q.w, c1));
            if (s1 < bd[r]) { bd[r] = s1; bj[r] = j0 + 1; }
        }
    }

    // pack (monotone-transformed s, j) into u64: min_u64 == (min s, then min j)
    #pragma unroll
    for (int r = 0; r < ROWS; ++r) {
        u32 b = __float_as_uint(bd[r]);
        u32 t = b ^ ((u32)((int)b >> 31) | 0x80000000u);   // IEEE->monotone u32
        u64 key = ((u64)t << 32) | (u32)bj[r];
        #pragma unroll
        for (int off = 32; off; off >>= 1) {
            u64 ok = __shfl_xor(key, off);
            if (ok < key) key = ok;
        }
        if (lane == 0) redk[r * NW + wv] = key;
    }
    __syncthreads();                    // the kernel's only barrier

    // parallel epilogue: lanes 0..31 (wave 0); rows >= ROWS contribute zeros
    // so the 32-lane shfl reduction tree stays uniform.
    if (tid < 32) {
        const int r = tid;
        const bool active = (r < ROWS);
        float v0=0,v1=0,v2=0,v3=0,v4=0,v5=0,v6=0,v7=0,v8=0,v9=0,v10=0,v11=0;
        if (active) {
            u64 key = redk[r * NW + 0];
            #pragma unroll
            for (int w = 1; w < NW; ++w) {
                u64 ok = redk[r * NW + w];
                if (ok < key) key = ok;
            }
            const int jj = (int)(u32)key;
            const int gi = gi0 + r;
            const float2 qp = ((const float2*)w_pt0)[gi];
            const float2 qn = ((const float2*)(pt1 + (size_t)n * L1 * 2))[jj];
            const float dx = qp.x - qn.x, dy = qp.y - qn.y;
            const float l2 = sqrtf(dx * dx + dy * dy);     // exact d2

            const float thr = 8.0f * scale0[n * 2 + 0];
            const float sxd = ((float)W1C * scale1[n * 2 + 0] * 8.0f - 1.0f) * 0.5f;
            const float syd = ((float)H1C * scale1[n * 2 + 1] * 8.0f - 1.0f) * 0.5f;
            const float* im = score1 + (size_t)n * L1;

            // both mask interpretations (int32/float32 agree on word != 0)
            const float mw = (((const u32*)maskp)[gi] != 0u) ? 1.0f : 0.0f;
            const float mb = (((const unsigned char*)maskp)[gi] != 0) ? 1.0f : 0.0f;
            const float inthr = (l2 <= thr) ? 1.0f : 0.0f;

            const float s0v  = score0[gi];
            const float ssum = im[jj] + s0v;

            // bilinear grid-sample of score1 as 60x80 image, zeros outside
            const float gx = (qp.x / sxd) * 0.5f * (float)(W1C - 1);
            const float gy = (qp.y / syd) * 0.5f * (float)(H1C - 1);
            const float x0 = floorf(gx), y0 = floorf(gy);
            const float x1 = x0 + 1.0f,  y1 = y0 + 1.0f;
            const float wx1 = gx - x0, wx0 = 1.0f - wx1;
            const float wy1 = gy - y0, wy0 = 1.0f - wy1;

            auto corner = [&](float xf, float yf) -> float {
                bool inb = (xf >= 0.0f) && (xf <= (float)(W1C - 1)) &&
                           (yf >= 0.0f) && (yf <= (float)(H1C - 1));
                int xc = (int)fminf(fmaxf(xf, 0.0f), (float)(W1C - 1));
                int yc = (int)fminf(fmaxf(yf, 0.0f), (float)(H1C - 1));
                float v = im[yc * W1C + xc];
                return inb ? v : 0.0f;
            };
            const float res = corner(x0, y0) * wx0 * wy0
                            + corner(x1, y0) * wx1 * wy0
                            + corner(x0, y1) * wx0 * wy1
                            + corner(x1, y1) * wx1 * wy1;
            const float dsc = res - s0v;
            const float dsq = dsc * dsc;

            const float dvw = inthr * mw, dvb = inthr * mb;
            v0 = dvw;         v1 = l2 * dvw;   v2  = ssum * l2 * dvw;
            v3 = ssum * dvw;  v4 = mw;         v5  = dsq * mw;
            v6 = dvb;         v7 = l2 * dvb;   v8  = ssum * l2 * dvb;
            v9 = ssum * dvb;  v10 = mb;        v11 = dsq * mb;
        }
#define RED32(V) { V += __shfl_xor(V, 16); V += __shfl_xor(V, 8); \
                   V += __shfl_xor(V, 4);  V += __shfl_xor(V, 2); \
                   V += __shfl_xor(V, 1); }
        RED32(v0) RED32(v1) RED32(v2) RED32(v3) RED32(v4)  RED32(v5)
        RED32(v6) RED32(v7) RED32(v8) RED32(v9) RED32(v10) RED32(v11)
#undef RED32
        if (tid == 0) {
            partials[ 0 * NBLK + blk] = v0;  partials[ 1 * NBLK + blk] = v1;
            partials[ 2 * NBLK + blk] = v2;  partials[ 3 * NBLK + blk] = v3;
            partials[ 4 * NBLK + blk] = v4;  partials[ 5 * NBLK + blk] = v5;
            partials[ 6 * NBLK + blk] = v6;  partials[ 7 * NBLK + blk] = v7;
            partials[ 8 * NBLK + blk] = v8;  partials[ 9 * NBLK + blk] = v9;
            partials[10 * NBLK + blk] = v10; partials[11 * NBLK + blk] = v11;
        }
    }
}

// ---------------------------------------------------------------------------
// Finalize: one block. Detects mask format, reduces 12 partial arrays, emits.
// ---------------------------------------------------------------------------
__global__ __launch_bounds__(NT) void s2ld_finalize(
    const float* __restrict__ partials,
    const void*  __restrict__ maskp,
    float*       __restrict__ out)
{
    __shared__ float fin[12 * NW];
    __shared__ u32   sbad;

    const int tid  = threadIdx.x;
    const int lane = tid & 63;
    const int wv   = tid >> 6;

    if (tid == 0) sbad = 0u;
    __syncthreads();
    {
        // mask format detection (first 2400 words in-bounds for all layouts)
        u32 bad = 0u;
        const u32* mwp = (const u32*)maskp;
        for (int i = tid; i < 2400; i += NT) {
            u32 w = mwp[i];
            if (w != 0u && w != 1u && w != 0x3f800000u) bad = 1u;
        }
        atomicOr(&sbad, bad);
    }

    for (int k = 0; k < 12; ++k) {
        float s = 0.0f;
        for (int rbl = tid; rbl < NBLK; rbl += NT) s += partials[k * NBLK + rbl];
        #pragma unroll
        for (int off = 32; off; off >>= 1) s += __shfl_xor(s, off);
        if (lane == 0) fin[k * NW + wv] = s;
    }
    __syncthreads();

    if (tid == 0) {
        const int o = (sbad == 0u) ? 0 : 6;   // word-format vs byte-format
        float S[6];
        #pragma unroll
        for (int k = 0; k < 6; ++k) {
            float s = 0.0f;
            #pragma unroll
            for (int w = 0; w < NW; ++w) s += fin[(o + k) * NW + w];
            S[k] = s;
        }
        const float den = fmaxf(S[0], 1.0f);
        const float lm  = S[1] / den;
        out[0] = lm;                              // loc_loss_mean
        out[1] = (S[2] - lm * S[3]) / den;        // rep_loss_mean
        out[2] = 2.0f * S[5] / fmaxf(S[4], 1.0f); // score_loss
    }
}

extern "C" void kernel_launch(void* const* d_in, const int* in_sizes, int n_in,
                              void* d_out, int out_size, void* d_ws, size_t ws_size,
                              hipStream_t stream) {
    const float* w_pt0  = (const float*)d_in[0];
    const float* pt1    = (const float*)d_in[1];
    const void*  maskp  =               d_in[2];
    const float* score0 = (const float*)d_in[3];
    const float* score1 = (const float*)d_in[4];
    // d_in[5] = image1 (zeros) -- unused
    const float* scale0 = (const float*)d_in[6];
    const float* scale1 = (const float*)d_in[7];

    float* partials = (float*)d_ws;   // 12 * 400 * 4 B, fully rewritten

    s2ld_main<<<NBLK, NT, 0, stream>>>(w_pt0, pt1, maskp, score0, score1,
                                       scale0, scale1, partials);
    s2ld_finalize<<<1, NT, 0, stream>>>(partials, maskp, (float*)d_out);
}